// Round 3
// baseline (343.229 us; speedup 1.0000x reference)
//
#include <hip/hip_runtime.h>
#include <hip/hip_bf16.h>

// Problem: B=4, T=2048, D=1024, H=16, HD=64
#define B_  4
#define T_  2048
#define D_  1024
#define H_  16
#define HD_ 64

typedef short s16x8 __attribute__((ext_vector_type(8)));
typedef short s16x4 __attribute__((ext_vector_type(4)));
typedef float f32x4 __attribute__((ext_vector_type(4)));

#define MFMA32(a, b, c) __builtin_amdgcn_mfma_f32_16x16x32_bf16(a, b, c, 0, 0, 0)
#define MFMA16(a, b, c) __builtin_amdgcn_mfma_f32_16x16x16bf16_1k(a, b, c, 0, 0, 0)

__device__ __forceinline__ unsigned short f2bf(float f) {
  unsigned u = __builtin_bit_cast(unsigned, f);
  u += 0x7fffu + ((u >> 16) & 1u);   // RNE
  return (unsigned short)(u >> 16);
}

#define GLOAD_LDS16(src, dst)                                            \
  __builtin_amdgcn_global_load_lds(                                      \
      (__attribute__((address_space(1))) void*)(void*)(src),             \
      (__attribute__((address_space(3))) void*)(dst), 16, 0, 0)

// ---------------------------------------------------------------- convert x
__global__ __launch_bounds__(256) void convert_x_kernel(
    const float* __restrict__ in, unsigned short* __restrict__ out, int n8) {
  int i = blockIdx.x * 256 + threadIdx.x;
  if (i >= n8) return;
  const float4* p = ((const float4*)in) + (size_t)i * 2;
  float4 a = p[0], b = p[1];
  s16x8 o;
  o[0] = (short)f2bf(a.x); o[1] = (short)f2bf(a.y);
  o[2] = (short)f2bf(a.z); o[3] = (short)f2bf(a.w);
  o[4] = (short)f2bf(b.x); o[5] = (short)f2bf(b.y);
  o[6] = (short)f2bf(b.z); o[7] = (short)f2bf(b.w);
  *(((s16x8*)out) + i) = o;
}

// ------------------------------------------------- transpose W [K][N] -> bf16 [N][K]
__global__ __launch_bounds__(256) void transpose_w_kernel(
    const float* __restrict__ W, unsigned short* __restrict__ Wt, int K, int N) {
  __shared__ float tile[32][33];
  int n0 = blockIdx.x * 32, k0 = blockIdx.y * 32;
  int tx = threadIdx.x & 31, ty = threadIdx.x >> 5;  // ty 0..7
#pragma unroll
  for (int j = 0; j < 4; ++j) {
    int k = ty + j * 8;
    tile[k][tx] = W[(size_t)(k0 + k) * N + n0 + tx];
  }
  __syncthreads();
#pragma unroll
  for (int j = 0; j < 4; ++j) {
    int n = ty + j * 8;
    Wt[(size_t)(n0 + n) * K + k0 + tx] = f2bf(tile[tx][n]);
  }
}

// ---------------------------------------------------------------- GEMM 128x128
// m97-structure: linear LDS, global_load_lds w=16, no swizzle.
// C[M,N] = A[M,K] * Bt[N,K]^T + bias ; A,Bt bf16 ; OUTF32 ? f32 : bf16 out
template <int OUTF32>
__global__ __launch_bounds__(256) void gemm_kernel(
    const unsigned short* __restrict__ A, const unsigned short* __restrict__ Bt,
    const float* __restrict__ bias, void* __restrict__ Cout, int M, int N, int K) {
  __shared__ char lds[32768];
  char* Al = lds;
  char* Bl = lds + 16384;
  const int n0 = blockIdx.x * 128, m0 = blockIdx.y * 128;
  const int w = threadIdx.x >> 6, lane = threadIdx.x & 63;
  const int l15 = lane & 15, g = lane >> 4;
  const int wr = w >> 1, wc = w & 1;
  const int srow = (lane >> 3);       // 0..7 within chunk
  const int u = lane & 7;             // d-octet 0..7
  f32x4 acc[4][4] = {};

  for (int kt = 0; kt < K; kt += 64) {
    __syncthreads();
#pragma unroll
    for (int i = 0; i < 4; ++i) {
      int c = w * 4 + i;              // chunk 0..15, 8 rows each
      int row = c * 8 + srow;         // 0..127
      const unsigned short* srcA = A + (size_t)(m0 + row) * K + kt + u * 8;
      GLOAD_LDS16(srcA, Al + c * 1024);
      const unsigned short* srcB = Bt + (size_t)(n0 + row) * K + kt + u * 8;
      GLOAD_LDS16(srcB, Bl + c * 1024);
    }
    __syncthreads();
#pragma unroll
    for (int kk = 0; kk < 2; ++kk) {
      s16x8 af[4], bfr[4];
#pragma unroll
      for (int mi = 0; mi < 4; ++mi) {
        int row = wr * 64 + mi * 16 + l15;
        af[mi] = *(const s16x8*)(Al + row * 128 + kk * 64 + g * 16);
      }
#pragma unroll
      for (int ni = 0; ni < 4; ++ni) {
        int row = wc * 64 + ni * 16 + l15;
        bfr[ni] = *(const s16x8*)(Bl + row * 128 + kk * 64 + g * 16);
      }
#pragma unroll
      for (int mi = 0; mi < 4; ++mi)
#pragma unroll
        for (int ni = 0; ni < 4; ++ni)
          acc[mi][ni] = MFMA32(af[mi], bfr[ni], acc[mi][ni]);
    }
  }
  // epilogue: D layout col=lane&15, row=(lane>>4)*4+r
#pragma unroll
  for (int ni = 0; ni < 4; ++ni) {
    int col = n0 + wc * 64 + ni * 16 + l15;
    float bv = bias[col];
#pragma unroll
    for (int mi = 0; mi < 4; ++mi) {
      int row = m0 + wr * 64 + mi * 16 + g * 4;
#pragma unroll
      for (int r = 0; r < 4; ++r) {
        float v = acc[mi][ni][r] + bv;
        if (OUTF32)
          ((float*)Cout)[(size_t)(row + r) * N + col] = v;
        else
          ((unsigned short*)Cout)[(size_t)(row + r) * N + col] = f2bf(v);
      }
    }
  }
}

// ---------------------------------------------------------------- attention
// grid (T/64, B*H), 256 thr (4 waves). Wave w owns q rows [q0+16w, q0+16w+16).
// Swapped QK^T: S^T = mfma(A=K, B=Q) -> lane holds keys (g*4+r), q col = l15.
// V staged TRANSPOSED in LDS: Vt[d][key], padded stride 72; PV A-frag is a
// natural ds_read_b64 (no tr-read, no asm).
#define VT_STR 72
__global__ __launch_bounds__(256) void attn_kernel(
    const unsigned short* __restrict__ qkv, unsigned short* __restrict__ yatt) {
  __shared__ char lds[8192 + 64 * VT_STR * 2];  // K tile 8KB, Vt 9KB; reused for y-stage
  const int tq = blockIdx.x;
  const int bh = blockIdx.y;
  const int b = bh >> 4, h = bh & 15;
  const int q0 = tq * 64;
  const int w = threadIdx.x >> 6;
  const int lane = threadIdx.x & 63;
  const int l15 = lane & 15, g = lane >> 4;

  const size_t rowstride = 3 * D_;  // 3072 elems per token row
  const unsigned short* Qb = qkv + (size_t)b * T_ * rowstride + h * HD_;
  const unsigned short* Kb = Qb + D_;
  const unsigned short* Vb = Qb + 2 * D_;

  // Q fragments (B operand of 16x16x32): col=l15 -> q row q0+16w+l15 ; k=g*8+j -> d
  const unsigned short* qrow = Qb + (size_t)(q0 + w * 16 + l15) * rowstride;
  const s16x8 qf0 = *(const s16x8*)(qrow + g * 8);
  const s16x8 qf1 = *(const s16x8*)(qrow + 32 + g * 8);

  float m = -1e30f, rs = 0.0f;
  f32x4 acc[4] = {};  // y^T: acc[db] holds d = db*16 + g*4 + r, q col = l15

  char* Klds = lds;
  unsigned short* Vt = (unsigned short*)(lds + 8192);
  const int srow = lane >> 3, u = lane & 7;
  const int vkey = w * 16 + (lane >> 2);  // 0..63
  const int vdb = lane & 3;               // 0..3
  const float SC = 0.18033688011112042f;  // log2(e)/sqrt(64)

  const int ntiles = tq + 1;
  for (int kt = 0; kt < ntiles; ++kt) {
    __syncthreads();
    // stage K tile [64 keys][64 d] linear
#pragma unroll
    for (int i = 0; i < 2; ++i) {
      int c = w * 2 + i;
      int row = c * 8 + srow;
      const unsigned short* src = Kb + (size_t)(kt * 64 + row) * rowstride + u * 8;
      GLOAD_LDS16(src, Klds + c * 1024);
    }
    // stage V transposed: Vt[d][key], each thread owns (key=vkey, d-block=vdb)
    {
      const unsigned short* src = Vb + (size_t)(kt * 64 + vkey) * rowstride + vdb * 16;
      s16x8 v0 = *(const s16x8*)(src);
      s16x8 v1 = *(const s16x8*)(src + 8);
#pragma unroll
      for (int j = 0; j < 8; ++j) {
        Vt[(vdb * 16 + j) * VT_STR + vkey] = (unsigned short)v0[j];
        Vt[(vdb * 16 + 8 + j) * VT_STR + vkey] = (unsigned short)v1[j];
      }
    }
    __syncthreads();

    // QK^T for all 4 key groups of this 64-key tile
    float tv[16];
#pragma unroll
    for (int kk = 0; kk < 4; ++kk) {
      f32x4 s = {};
      int key = kk * 16 + l15;
      s16x8 kf0 = *(const s16x8*)(Klds + key * 128 + g * 16);
      s16x8 kf1 = *(const s16x8*)(Klds + key * 128 + 64 + g * 16);
      s = MFMA32(kf0, qf0, s);
      s = MFMA32(kf1, qf1, s);
#pragma unroll
      for (int r = 0; r < 4; ++r) tv[kk * 4 + r] = s[r] * SC;
    }
    if (kt == tq) {  // diagonal tile: causal mask
      int q = q0 + w * 16 + l15;
#pragma unroll
      for (int kk = 0; kk < 4; ++kk)
#pragma unroll
        for (int r = 0; r < 4; ++r) {
          int key = kt * 64 + kk * 16 + g * 4 + r;
          if (key > q) tv[kk * 4 + r] = -1e30f;
        }
    }
    // online softmax (base-2 units)
    float tm = tv[0];
#pragma unroll
    for (int i = 1; i < 16; ++i) tm = fmaxf(tm, tv[i]);
    tm = fmaxf(tm, __shfl_xor(tm, 16));
    tm = fmaxf(tm, __shfl_xor(tm, 32));
    float mn = fmaxf(m, tm);
    float corr = exp2f(m - mn);
    m = mn;
    rs *= corr;
#pragma unroll
    for (int i = 0; i < 4; ++i) {
      acc[i][0] *= corr; acc[i][1] *= corr; acc[i][2] *= corr; acc[i][3] *= corr;
    }
    s16x4 pb[4];
    float ps = 0.f;
#pragma unroll
    for (int kk = 0; kk < 4; ++kk)
#pragma unroll
      for (int r = 0; r < 4; ++r) {
        float p = exp2f(tv[kk * 4 + r] - m);
        ps += p;
        pb[kk][r] = (short)f2bf(p);
      }
    rs += ps;
    // PV: y^T += mfma(A = Vt fragment, B = P^T)
#pragma unroll
    for (int kk = 0; kk < 4; ++kk) {
#pragma unroll
      for (int db = 0; db < 4; ++db) {
        s16x4 vf = *(const s16x4*)(Vt + (db * 16 + l15) * VT_STR + kk * 16 + g * 4);
        acc[db] = MFMA16(vf, pb[kk], acc[db]);
      }
    }
  }
  // final denominator (sum partial rowsums across the 4 lane-groups)
  float rtot = rs + __shfl_xor(rs, 16);
  rtot += __shfl_xor(rtot, 32);
  float inv = 1.0f / rtot;

  // transpose y^T -> y via LDS, coalesced bf16 store
  __syncthreads();
  unsigned short* ylds = (unsigned short*)lds;  // [64 d][66]
#pragma unroll
  for (int db = 0; db < 4; ++db)
#pragma unroll
    for (int r = 0; r < 4; ++r) {
      int d = db * 16 + g * 4 + r;
      ylds[d * 66 + w * 16 + l15] = f2bf(acc[db][r] * inv);
    }
  __syncthreads();
  int qq = threadIdx.x >> 2;
  int dc = (threadIdx.x & 3) * 16;
  s16x8 o1, o2;
#pragma unroll
  for (int j = 0; j < 8; ++j) {
    o1[j] = (short)ylds[(dc + j) * 66 + qq];
    o2[j] = (short)ylds[(dc + 8 + j) * 66 + qq];
  }
  unsigned short* dst = yatt + (size_t)(b * T_ + q0 + qq) * D_ + h * HD_ + dc;
  *(s16x8*)(dst) = o1;
  *(s16x8*)(dst + 8) = o2;
}

// ---------------------------------------------------------------- launcher
extern "C" void kernel_launch(void* const* d_in, const int* in_sizes, int n_in,
                              void* d_out, int out_size, void* d_ws, size_t ws_size,
                              hipStream_t stream) {
  const float* x     = (const float*)d_in[0];
  const float* Wqkv  = (const float*)d_in[1];
  const float* bqkv  = (const float*)d_in[2];
  const float* Wproj = (const float*)d_in[3];
  const float* bproj = (const float*)d_in[4];
  float* out = (float*)d_out;

  // workspace layout (bf16 buffers), 72 MiB total; yb aliases xb (dead after gemm<0>)
  unsigned short* xb   = (unsigned short*)d_ws;              // [8192][1024]
  unsigned short* Wqb  = xb + (size_t)8192 * 1024;           // [3072][1024] (W_qkv^T)
  unsigned short* Wpb  = Wqb + (size_t)3072 * 1024;          // [1024][1024] (W_proj^T)
  unsigned short* qkvb = Wpb + (size_t)1024 * 1024;          // [8192][3072]
  unsigned short* yb   = xb;                                 // alias: x dead after gemm<0>

  convert_x_kernel<<<dim3(4096), dim3(256), 0, stream>>>(x, xb, 8192 * 1024 / 8);
  transpose_w_kernel<<<dim3(96, 32), dim3(256), 0, stream>>>(Wqkv, Wqb, 1024, 3072);
  transpose_w_kernel<<<dim3(32, 32), dim3(256), 0, stream>>>(Wproj, Wpb, 1024, 1024);
  gemm_kernel<0><<<dim3(24, 64), dim3(256), 0, stream>>>(xb, Wqb, bqkv, qkvb, 8192, 3072, 1024);
  attn_kernel<<<dim3(32, 64), dim3(256), 0, stream>>>(qkvb, yb);
  gemm_kernel<1><<<dim3(8, 64), dim3(256), 0, stream>>>(yb, Wpb, bproj, out, 8192, 1024, 1024);
}